// Round 7
// baseline (336.150 us; speedup 1.0000x reference)
//
#include <hip/hip_runtime.h>
#include <math.h>

// WavelengthDependentPropagation: out = ifft2( fft2(x) * H(lam_c, fy, fx) )
// B=8, C=3, H=W=1024.  y-chunked scratch layout + 2-batch L3-resident schedule.
//   T2 layout (per 12-img batch): [img:12][yg8:128][x:1024][yi:8] complex
//     -> K1 writes contiguous 64KB/block, K3 reads contiguous 64KB/block,
//        K2 reads/writes 64B line-exact chunks (L2/L3-backed).
//   K0: Htab2 in the same chunked layout (3 wavelengths), pre-scaled by 2^-20
//   per batch h in {0,1}: K1 (row FFT) -> K2 (col FFT * H * inv col FFT)
//                         -> K3 (inv row FFT -> planes), T2 region reused.

#define NIMG 24
#define HALF 12

__device__ __forceinline__ float2 cadd(float2 a, float2 b){ return make_float2(a.x+b.x, a.y+b.y); }
__device__ __forceinline__ float2 csub(float2 a, float2 b){ return make_float2(a.x-b.x, a.y-b.y); }
__device__ __forceinline__ float2 cmul(float2 a, float c, float s){ return make_float2(a.x*c - a.y*s, a.x*s + a.y*c); }

// swizzled byte offset within an 8KB column buffer for complex index j
__device__ __forceinline__ int SW(int j) {
    int b = j << 3;
    return b ^ (((b >> 7) & 7) << 4);
}

// ---------------- transfer function (mirrors the jnp fp32 chain exactly) ----
__device__ __forceinline__ float2 computeH(float lam, int ky, int kx) {
    int iy = (ky < 512) ? ky : ky - 1024;
    int ix = (kx < 512) ? kx : kx - 1024;
    const double recip = 1.0 / (1024.0 * 8e-06);
    float fy = (float)((double)iy * recip);
    float fx = (float)((double)ix * recip);
    float f2  = __fadd_rn(__fmul_rn(fy, fy), __fmul_rn(fx, fx));
    float l2  = __fmul_rn(lam, lam);
    float arg = __fsub_rn(1.0f, __fmul_rn(l2, f2));
    float2 h = make_float2(0.0f, 0.0f);
    if (arg > 0.0f) {
        float t  = __fdiv_rn(6.28318530717958647692f, lam);
        t        = __fmul_rn(t, 0.05f);
        float kz = __fmul_rn(t, __fsqrt_rn(arg));
        double s, c;
        sincos((double)kz, &s, &c);
        const float sc = 9.5367431640625e-07f;              // 2^-20
        h = make_float2((float)c * sc, (float)s * sc);
    }
    return h;
}

// Htab2[((c*128 + yg8)*1024 + kx)*8 + yi] = H(ky = 8*yg8+yi, kx) * 2^-20
__global__ __launch_bounds__(256) void build_H_C8(float2* __restrict__ Htab,
                                                  const float* __restrict__ wl) {
    int idx = blockIdx.x * 256 + threadIdx.x;    // 0 .. 3*1M
    int c   = idx >> 20;
    int rem = idx & 1048575;
    int yg8 = rem >> 13;
    int kx  = (rem >> 3) & 1023;
    int yi  = rem & 7;
    Htab[idx] = computeH(wl[c], (yg8 << 3) | yi, kx);
}

// ---------------- radix-4 butterflies ---------------------------------------
template<int SIGN>
__device__ __forceinline__ void dft4nt(float2& a0, float2& a1, float2& a2, float2& a3) {
    float2 t0 = cadd(a0, a2), t1 = csub(a0, a2);
    float2 t2 = cadd(a1, a3), t3 = csub(a1, a3);
    a0 = cadd(t0, t2);
    a2 = csub(t0, t2);
    a1 = make_float2(t1.x - SIGN * t3.y, t1.y + SIGN * t3.x);
    a3 = make_float2(t1.x + SIGN * t3.y, t1.y - SIGN * t3.x);
}
template<int SIGN>
__device__ __forceinline__ void dft4(float2& a0, float2& a1, float2& a2, float2& a3,
                                     float c1, float s1) {
    float c2 = c1*c1 - s1*s1, s2 = 2.f*c1*s1;
    float c3 = c2*c1 - s2*s1, s3 = s2*c1 + c2*s1;
    a1 = cmul(a1, c1, s1);
    a2 = cmul(a2, c2, s2);
    a3 = cmul(a3, c3, s3);
    dft4nt<SIGN>(a0, a1, a2, a3);
}

#define WSYNC() do { asm volatile("s_waitcnt lgkmcnt(0)" ::: "memory"); \
                     __builtin_amdgcn_wave_barrier(); } while (0)

// ---------------- modular 1024-pt wave-private FFT pieces (verified R1-R6) ---
// Register layout for round-A input and round-C output: v[a][b] = pos l+64(a+4b).

__device__ __forceinline__ void ldsToRegs(char* cb, int l, float2 (&v)[4][4]) {
    const int swzE = (((l >> 4)    ) & 7) << 4;
    const int swzO = (((l >> 4) + 4) & 7) << 4;
    char* rbE = cb + ((8 * l) ^ swzE);
    char* rbO = cb + ((8 * l) ^ swzO);
    #pragma unroll
    for (int k = 0; k < 4; ++k) {
        #pragma unroll
        for (int r = 0; r < 4; ++r) {
            const int tt = k + 4 * r;
            v[k][r] = *(const float2*)(((tt & 1) ? rbO : rbE) + 512 * tt);
        }
    }
}
__device__ __forceinline__ void regsToLds(char* cb, int l, const float2 (&v)[4][4]) {
    const int swzE = (((l >> 4)    ) & 7) << 4;
    const int swzO = (((l >> 4) + 4) & 7) << 4;
    char* rbE = cb + ((8 * l) ^ swzE);
    char* rbO = cb + ((8 * l) ^ swzO);
    #pragma unroll
    for (int m = 0; m < 4; ++m) {
        #pragma unroll
        for (int q = 0; q < 4; ++q) {
            const int tt = m + 4 * q;
            *(float2*)(((tt & 1) ? rbO : rbE) + 512 * tt) = v[m][q];
        }
    }
}

template<int SIGN>
__device__ __forceinline__ void fftA(char* cb, int l, float2 (&v)[4][4]) {
    const float SPI8 = SIGN * 0.39269908169872415481f;     // pi/8
    #pragma unroll
    for (int k = 0; k < 4; ++k) dft4nt<SIGN>(v[k][0], v[k][1], v[k][2], v[k][3]);
    dft4nt<SIGN>(v[0][0], v[1][0], v[2][0], v[3][0]);
    #pragma unroll
    for (int q = 1; q < 4; ++q) {
        float s1, c1; __sincosf((float)q * SPI8, &s1, &c1);
        dft4<SIGN>(v[0][q], v[1][q], v[2][q], v[3][q], c1, s1);
    }
    char* wb = cb + 128 * l;
    const int L7 = l & 7;
    #pragma unroll
    for (int p = 0; p < 4; ++p) {
        *(float4*)(wb + 16 * ((2*p+0) ^ L7)) =
            make_float4(v[p][0].x, v[p][0].y, v[p][1].x, v[p][1].y);
        *(float4*)(wb + 16 * ((2*p+1) ^ L7)) =
            make_float4(v[p][2].x, v[p][2].y, v[p][3].x, v[p][3].y);
    }
}

template<int SIGN>
__device__ __forceinline__ void fftB(char* cb, int l) {
    const float SPI32  = SIGN * 0.09817477042468103870f;   // pi/32
    const float SPI128 = SIGN * 0.02454369260617025967f;   // pi/128
    const int swzE = (((l >> 4)    ) & 7) << 4;
    const int swzO = (((l >> 4) + 4) & 7) << 4;
    char* rbE = cb + ((8 * l) ^ swzE);
    char* rbO = cb + ((8 * l) ^ swzO);
    float2 v[4][4];
    #pragma unroll
    for (int k = 0; k < 4; ++k) {
        #pragma unroll
        for (int r = 0; r < 4; ++r) {
            const int tt = k + 4 * r;
            v[k][r] = *(const float2*)(((tt & 1) ? rbO : rbE) + 512 * tt);
        }
    }
    const int jm2 = l & 15;
    float s1, c1; __sincosf((float)jm2 * SPI32, &s1, &c1);
    #pragma unroll
    for (int k = 0; k < 4; ++k) dft4<SIGN>(v[k][0], v[k][1], v[k][2], v[k][3], c1, s1);
    const int lo8 = 8 * (l & 15);
    const int hi  = 2048 * (l >> 4);
    #pragma unroll
    for (int q = 0; q < 4; ++q) {
        float s1b, c1b; __sincosf((float)(jm2 + 16 * q) * SPI128, &s1b, &c1b);
        dft4<SIGN>(v[0][q], v[1][q], v[2][q], v[3][q], c1b, s1b);
        #pragma unroll
        for (int p = 0; p < 4; ++p) {
            const int K = ((q + 4 * p) & 7) << 4;
            *(float2*)(cb + (lo8 ^ K) + hi + 128 * q + 512 * p) = v[p][q];
        }
    }
}

template<int SIGN>
__device__ __forceinline__ void fftC(int l, float2 (&v)[4][4]) {
    const float SPI512 = SIGN * 0.00613592315154256492f;   // pi/512
    #pragma unroll
    for (int m = 0; m < 4; ++m) {
        float s1, c1; __sincosf((float)(l + 64 * m) * SPI512, &s1, &c1);
        dft4<SIGN>(v[m][0], v[m][1], v[m][2], v[m][3], c1, s1);
    }
}

// ---------------- K1: row FFT -> contiguous chunked store --------------------
// 512 thr = 8 waves, 8 rows/block, 64KB LDS, 2 blocks/CU.
__global__ __launch_bounds__(512, 4) void k1_rows_C8(const float* __restrict__ xr,
                                                     const float* __restrict__ xi,
                                                     float2* __restrict__ T,
                                                     int imgBase) {
    __shared__ float4 ldsb[4096];                 // 64 KB
    char* lds = (char*)ldsb;
    const int t = threadIdx.x, w = t >> 6, l = t & 63;
    const int img_l = blockIdx.x >> 7;            // 0..11
    const int yg8   = blockIdx.x & 127;
    const int y0    = yg8 << 3;
    char* cb = lds + 8192 * w;                    // wave w owns row y0+w

    // direct global->reg load in round-A layout (256B/instr coalesced)
    const long long gib = (long long)(imgBase + img_l) << 20;
    const float* rr = xr + gib + (long long)(y0 + w) * 1024;
    const float* ri = xi + gib + (long long)(y0 + w) * 1024;
    float2 v[4][4];
    #pragma unroll
    for (int k = 0; k < 4; ++k) {
        #pragma unroll
        for (int r = 0; r < 4; ++r) {
            const int p = l + 64 * (k + 4 * r);
            v[k][r] = make_float2(rr[p], ri[p]);
        }
    }
    fftA<-1>(cb, l, v); WSYNC();
    fftB<-1>(cb, l);    WSYNC();
    ldsToRegs(cb, l, v);
    fftC<-1>(l, v);
    WSYNC();
    regsToLds(cb, l, v);
    __syncthreads();

    // contiguous chunked store: thread t owns columns t and t+512.
    // chunk (img_l, yg8, x) at complex offset img_l*1M + yg8*8192 + x*8.
    {
        const long long cb0 = ((long long)img_l << 20) + (long long)yg8 * 8192;
        #pragma unroll
        for (int c2 = 0; c2 < 2; ++c2) {
            const int x = t + 512 * c2;
            const int sx = SW(x);
            float4* dst = (float4*)(T + cb0 + (long long)x * 8);
            #pragma unroll
            for (int p = 0; p < 4; ++p) {
                float2 a = *(const float2*)(lds + 8192 * (2 * p)     + sx);
                float2 b = *(const float2*)(lds + 8192 * (2 * p + 1) + sx);
                dst[p] = make_float4(a.x, a.y, b.x, b.y);
            }
        }
    }
}

// ---------------- K2: column pass, wave-private, chunked line-exact I/O ------
// 256 thr = 4 waves, one column per wave, 32KB LDS, zero block barriers.
__global__ __launch_bounds__(256, 4) void k2_cols_C8(float2* __restrict__ T,
                                                     const float2* __restrict__ Htab,
                                                     const float* __restrict__ wl) {
    __shared__ float4 ldsb[2048];                 // 32KB
    char* lds = (char*)ldsb;
    const int t = threadIdx.x, w = t >> 6, l = t & 63;
    const int img_l = blockIdx.x >> 8;            // 0..11
    const int x     = ((blockIdx.x & 255) << 2) + w;
    const int lamIdx = img_l % 3;                 // img global %3 == img_l %3 (12%3==0)
    char* cb = lds + 8192 * w;

    // per-lane chunk offset: y = l + 64*t_idx -> yg8 = 8*t_idx + (l>>3), yi = l&7
    const int laneOff = ((l >> 3) << 13) + x * 8 + (l & 7);   // complex units
    const int ib = (int)(img_l << 20);

    float2 v[4][4];
    #pragma unroll
    for (int k = 0; k < 4; ++k) {
        #pragma unroll
        for (int r = 0; r < 4; ++r)
            v[k][r] = T[ib + laneOff + (k + 4 * r) * 65536];
    }
    fftA<-1>(cb, l, v); WSYNC();
    fftB<-1>(cb, l);    WSYNC();

    // H loads issued here (cover latency under round C)
    float2 h[4][4];
    if (Htab) {
        const int hb = lamIdx << 20;
        #pragma unroll
        for (int m = 0; m < 4; ++m) {
            #pragma unroll
            for (int q = 0; q < 4; ++q)
                h[m][q] = Htab[hb + laneOff + (m + 4 * q) * 65536];
        }
    } else {
        const float lam = wl[lamIdx];
        #pragma unroll
        for (int m = 0; m < 4; ++m) {
            #pragma unroll
            for (int q = 0; q < 4; ++q)
                h[m][q] = computeH(lam, l + 64 * (m + 4 * q), x);
        }
    }

    ldsToRegs(cb, l, v);
    fftC<-1>(l, v);

    // *H in registers
    #pragma unroll
    for (int m = 0; m < 4; ++m) {
        #pragma unroll
        for (int q = 0; q < 4; ++q) {
            float2 a = v[m][q], hh = h[m][q];
            v[m][q] = make_float2(a.x * hh.x - a.y * hh.y, a.x * hh.y + a.y * hh.x);
        }
    }
    WSYNC();   // order C-reads before inverse A-writes

    fftA<1>(cb, l, v); WSYNC();
    fftB<1>(cb, l);    WSYNC();
    ldsToRegs(cb, l, v);
    fftC<1>(l, v);

    #pragma unroll
    for (int m = 0; m < 4; ++m) {
        #pragma unroll
        for (int q = 0; q < 4; ++q)
            T[ib + laneOff + (m + 4 * q) * 65536] = v[m][q];
    }
}

// ---------------- K3: contiguous chunked gather + inv row FFT -> planes ------
// 512 thr = 8 waves, 8 rows/block, 64KB LDS, 2 blocks/CU.
__global__ __launch_bounds__(512, 4) void k3_irows_C8(const float2* __restrict__ T,
                                                      float* __restrict__ outr,
                                                      float* __restrict__ outi,
                                                      int imgBase) {
    __shared__ float4 ldsb[4096];                 // 64 KB
    char* lds = (char*)ldsb;
    const int t = threadIdx.x, w = t >> 6, l = t & 63;
    const int img_l = blockIdx.x >> 7;
    const int yg8   = blockIdx.x & 127;
    const int y0    = yg8 << 3;

    // contiguous gather: thread t reads 64B chunks of columns t and t+512
    {
        const long long cb0 = ((long long)img_l << 20) + (long long)yg8 * 8192;
        #pragma unroll
        for (int c2 = 0; c2 < 2; ++c2) {
            const int x = t + 512 * c2;
            const int sx = SW(x);
            const float4* src = (const float4*)(T + cb0 + (long long)x * 8);
            #pragma unroll
            for (int p = 0; p < 4; ++p) {
                float4 g = src[p];                // (y0+2p, y0+2p+1) of col x
                *(float2*)(lds + 8192 * (2 * p)     + sx) = make_float2(g.x, g.y);
                *(float2*)(lds + 8192 * (2 * p + 1) + sx) = make_float2(g.z, g.w);
            }
        }
    }
    __syncthreads();

    char* cb = lds + 8192 * w;                    // wave w owns row y0+w
    float2 v[4][4];
    ldsToRegs(cb, l, v);
    fftA<1>(cb, l, v); WSYNC();
    fftB<1>(cb, l);    WSYNC();
    ldsToRegs(cb, l, v);
    fftC<1>(l, v);

    // direct store to planes (coalesced)
    const long long gib = (long long)(imgBase + img_l) << 20;
    float* pr = outr + gib + (long long)(y0 + w) * 1024;
    float* pi = outi + gib + (long long)(y0 + w) * 1024;
    #pragma unroll
    for (int m = 0; m < 4; ++m) {
        #pragma unroll
        for (int q = 0; q < 4; ++q) {
            const int p = l + 64 * (m + 4 * q);
            pr[p] = v[m][q].x;
            pi[p] = v[m][q].y;
        }
    }
}

// ---------------- launch ------------------------------------------------------
extern "C" void kernel_launch(void* const* d_in, const int* in_sizes, int n_in,
                              void* d_out, int out_size, void* d_ws, size_t ws_size,
                              hipStream_t stream) {
    const float* xr = (const float*)d_in[0];
    const float* xi = (const float*)d_in[1];
    const float* wl = (const float*)d_in[2];
    float* out = (float*)d_out;

    const size_t planeElems = (size_t)NIMG * 1024 * 1024;            // 24M
    float2* T = (float2*)d_ws;                                       // 96 MB (reused)
    const size_t needT = (size_t)HALF * 1024 * 1024 * sizeof(float2);
    const size_t needH = (size_t)3 * 1024 * 1024 * sizeof(float2);   // 24 MB
    float2* Htab = nullptr;
    if (ws_size >= needT + needH) {
        Htab = (float2*)((char*)d_ws + needT);
        build_H_C8<<<12288, 256, 0, stream>>>(Htab, wl);
    }
    for (int h = 0; h < 2; ++h) {
        const int imgBase = h * HALF;
        k1_rows_C8<<<HALF * 128, 512, 0, stream>>>(xr, xi, T, imgBase);
        k2_cols_C8<<<HALF * 256, 256, 0, stream>>>(T, Htab, wl);
        k3_irows_C8<<<HALF * 128, 512, 0, stream>>>(T, out, out + planeElems, imgBase);
    }
}

// Round 8
// 304.237 us; speedup vs baseline: 1.1049x; 1.1049x over previous
//
#include <hip/hip_runtime.h>
#include <math.h>

// WavelengthDependentPropagation: out = ifft2( fft2(x) * H(lam_c, fy, fx) )
// B=8, C=3, H=W=1024.  Transposed-spectrum pipeline.
//   T layout: [img:24][x:1024][y:1024] complex (column x contiguous in y)
//   K0: Htab[lam][kx][ky] (T orientation), pre-scaled by 2^-20
//   K1: 16 rows/block row FFT; store-friendly LDS relayout; cooperative
//       FULL-128B-LINE transposed store (8 lanes per line -> no partial sectors)
//   K2: one wave per column: global->regs -> FFT -> *H (regs) -> iFFT -> store
//   K3: full-line gather -> LDS -> row iFFT -> direct register store to planes

#define NIMG 24

__device__ __forceinline__ float2 cadd(float2 a, float2 b){ return make_float2(a.x+b.x, a.y+b.y); }
__device__ __forceinline__ float2 csub(float2 a, float2 b){ return make_float2(a.x-b.x, a.y-b.y); }
__device__ __forceinline__ float2 cmul(float2 a, float c, float s){ return make_float2(a.x*c - a.y*s, a.x*s + a.y*c); }

// swizzled byte offset within an 8KB column buffer for complex index j
__device__ __forceinline__ int SW(int j) {
    int b = j << 3;
    return b ^ (((b >> 7) & 7) << 4);
}

// ---------------- transfer function (mirrors the jnp fp32 chain exactly) ----
__device__ __forceinline__ float2 computeH(float lam, int ky, int kx) {
    int iy = (ky < 512) ? ky : ky - 1024;
    int ix = (kx < 512) ? kx : kx - 1024;
    const double recip = 1.0 / (1024.0 * 8e-06);
    float fy = (float)((double)iy * recip);
    float fx = (float)((double)ix * recip);
    float f2  = __fadd_rn(__fmul_rn(fy, fy), __fmul_rn(fx, fx));
    float l2  = __fmul_rn(lam, lam);
    float arg = __fsub_rn(1.0f, __fmul_rn(l2, f2));
    float2 h = make_float2(0.0f, 0.0f);
    if (arg > 0.0f) {
        float t  = __fdiv_rn(6.28318530717958647692f, lam);
        t        = __fmul_rn(t, 0.05f);
        float kz = __fmul_rn(t, __fsqrt_rn(arg));
        double s, c;
        sincos((double)kz, &s, &c);
        const float sc = 9.5367431640625e-07f;              // 2^-20
        h = make_float2((float)c * sc, (float)s * sc);
    }
    return h;
}

// Htab[c][kx][ky]  (T orientation: contiguous in ky)
__global__ __launch_bounds__(256) void build_H_T(float2* __restrict__ Htab,
                                                 const float* __restrict__ wl) {
    int idx = blockIdx.x * 256 + threadIdx.x;
    int c   = idx >> 20;
    int rem = idx & 1048575;
    Htab[idx] = computeH(wl[c], rem & 1023, rem >> 10);
}

// ---------------- radix-4 butterflies ---------------------------------------
template<int SIGN>
__device__ __forceinline__ void dft4nt(float2& a0, float2& a1, float2& a2, float2& a3) {
    float2 t0 = cadd(a0, a2), t1 = csub(a0, a2);
    float2 t2 = cadd(a1, a3), t3 = csub(a1, a3);
    a0 = cadd(t0, t2);
    a2 = csub(t0, t2);
    a1 = make_float2(t1.x - SIGN * t3.y, t1.y + SIGN * t3.x);
    a3 = make_float2(t1.x + SIGN * t3.y, t1.y - SIGN * t3.x);
}
template<int SIGN>
__device__ __forceinline__ void dft4(float2& a0, float2& a1, float2& a2, float2& a3,
                                     float c1, float s1) {
    float c2 = c1*c1 - s1*s1, s2 = 2.f*c1*s1;
    float c3 = c2*c1 - s2*s1, s3 = s2*c1 + c2*s1;
    a1 = cmul(a1, c1, s1);
    a2 = cmul(a2, c2, s2);
    a3 = cmul(a3, c3, s3);
    dft4nt<SIGN>(a0, a1, a2, a3);
}

#define WSYNC() do { asm volatile("s_waitcnt lgkmcnt(0)" ::: "memory"); \
                     __builtin_amdgcn_wave_barrier(); } while (0)

// ---------------- modular 1024-pt wave-private FFT pieces (verified R1-R7) ---
// Register layout for round-A input and round-C output: v[a][b] = pos l+64(a+4b).

__device__ __forceinline__ void ldsToRegs(char* cb, int l, float2 (&v)[4][4]) {
    const int swzE = (((l >> 4)    ) & 7) << 4;
    const int swzO = (((l >> 4) + 4) & 7) << 4;
    char* rbE = cb + ((8 * l) ^ swzE);
    char* rbO = cb + ((8 * l) ^ swzO);
    #pragma unroll
    for (int k = 0; k < 4; ++k) {
        #pragma unroll
        for (int r = 0; r < 4; ++r) {
            const int tt = k + 4 * r;
            v[k][r] = *(const float2*)(((tt & 1) ? rbO : rbE) + 512 * tt);
        }
    }
}
__device__ __forceinline__ void regsToLds(char* cb, int l, const float2 (&v)[4][4]) {
    const int swzE = (((l >> 4)    ) & 7) << 4;
    const int swzO = (((l >> 4) + 4) & 7) << 4;
    char* rbE = cb + ((8 * l) ^ swzE);
    char* rbO = cb + ((8 * l) ^ swzO);
    #pragma unroll
    for (int m = 0; m < 4; ++m) {
        #pragma unroll
        for (int q = 0; q < 4; ++q) {
            const int tt = m + 4 * q;
            *(float2*)(((tt & 1) ? rbO : rbE) + 512 * tt) = v[m][q];
        }
    }
}

template<int SIGN>
__device__ __forceinline__ void fftA(char* cb, int l, float2 (&v)[4][4]) {
    const float SPI8 = SIGN * 0.39269908169872415481f;     // pi/8
    #pragma unroll
    for (int k = 0; k < 4; ++k) dft4nt<SIGN>(v[k][0], v[k][1], v[k][2], v[k][3]);
    dft4nt<SIGN>(v[0][0], v[1][0], v[2][0], v[3][0]);
    #pragma unroll
    for (int q = 1; q < 4; ++q) {
        float s1, c1; __sincosf((float)q * SPI8, &s1, &c1);
        dft4<SIGN>(v[0][q], v[1][q], v[2][q], v[3][q], c1, s1);
    }
    char* wb = cb + 128 * l;
    const int L7 = l & 7;
    #pragma unroll
    for (int p = 0; p < 4; ++p) {
        *(float4*)(wb + 16 * ((2*p+0) ^ L7)) =
            make_float4(v[p][0].x, v[p][0].y, v[p][1].x, v[p][1].y);
        *(float4*)(wb + 16 * ((2*p+1) ^ L7)) =
            make_float4(v[p][2].x, v[p][2].y, v[p][3].x, v[p][3].y);
    }
}

template<int SIGN>
__device__ __forceinline__ void fftB(char* cb, int l) {
    const float SPI32  = SIGN * 0.09817477042468103870f;   // pi/32
    const float SPI128 = SIGN * 0.02454369260617025967f;   // pi/128
    const int swzE = (((l >> 4)    ) & 7) << 4;
    const int swzO = (((l >> 4) + 4) & 7) << 4;
    char* rbE = cb + ((8 * l) ^ swzE);
    char* rbO = cb + ((8 * l) ^ swzO);
    float2 v[4][4];
    #pragma unroll
    for (int k = 0; k < 4; ++k) {
        #pragma unroll
        for (int r = 0; r < 4; ++r) {
            const int tt = k + 4 * r;
            v[k][r] = *(const float2*)(((tt & 1) ? rbO : rbE) + 512 * tt);
        }
    }
    const int jm2 = l & 15;
    float s1, c1; __sincosf((float)jm2 * SPI32, &s1, &c1);
    #pragma unroll
    for (int k = 0; k < 4; ++k) dft4<SIGN>(v[k][0], v[k][1], v[k][2], v[k][3], c1, s1);
    const int lo8 = 8 * (l & 15);
    const int hi  = 2048 * (l >> 4);
    #pragma unroll
    for (int q = 0; q < 4; ++q) {
        float s1b, c1b; __sincosf((float)(jm2 + 16 * q) * SPI128, &s1b, &c1b);
        dft4<SIGN>(v[0][q], v[1][q], v[2][q], v[3][q], c1b, s1b);
        #pragma unroll
        for (int p = 0; p < 4; ++p) {
            const int K = ((q + 4 * p) & 7) << 4;
            *(float2*)(cb + (lo8 ^ K) + hi + 128 * q + 512 * p) = v[p][q];
        }
    }
}

template<int SIGN>
__device__ __forceinline__ void fftC(int l, float2 (&v)[4][4]) {
    const float SPI512 = SIGN * 0.00613592315154256492f;   // pi/512
    #pragma unroll
    for (int m = 0; m < 4; ++m) {
        float s1, c1; __sincosf((float)(l + 64 * m) * SPI512, &s1, &c1);
        dft4<SIGN>(v[m][0], v[m][1], v[m][2], v[m][3], c1, s1);
    }
}

// ---------------- K1: 16 rows/block + full-line cooperative T store ----------
// 1024 thr = 16 waves, 128KB LDS.  Wave w FFTs row y0+w in its private 8KB.
// Then relayout to addr(x,yi) = x*128 + ((yi*8) ^ sx(x)),
//   sx(x) = ((x>>1)&7)<<4 | ((x>>4)&1)<<3, and store 128B lines cooperatively.
__global__ __launch_bounds__(1024) void k1_rows_T16(const float* __restrict__ xr,
                                                    const float* __restrict__ xi,
                                                    float2* __restrict__ T) {
    extern __shared__ char lds[];                 // 131072 bytes
    const int t = threadIdx.x, w = t >> 6, l = t & 63;
    const int img = blockIdx.x >> 6;
    const int y0  = (blockIdx.x & 63) << 4;
    const long long ib = (long long)img << 20;
    char* cb = lds + 8192 * w;                    // wave w owns row y0+w

    // direct global->reg load, round-A layout (256B/instr coalesced)
    const float* rr = xr + ib + (long long)(y0 + w) * 1024;
    const float* ri = xi + ib + (long long)(y0 + w) * 1024;
    float2 v[4][4];
    #pragma unroll
    for (int k = 0; k < 4; ++k) {
        #pragma unroll
        for (int r = 0; r < 4; ++r) {
            const int p = l + 64 * (k + 4 * r);
            v[k][r] = make_float2(rr[p], ri[p]);
        }
    }
    fftA<-1>(cb, l, v); WSYNC();
    fftB<-1>(cb, l);    WSYNC();
    ldsToRegs(cb, l, v);
    fftC<-1>(l, v);
    __syncthreads();                              // all waves done with scratch

    // relayout: element p of row w -> lds[p*128 + ((w*8) ^ sx(p))]
    {
        const int w8 = w << 3;
        #pragma unroll
        for (int m = 0; m < 4; ++m) {
            #pragma unroll
            for (int q = 0; q < 4; ++q) {
                const int p  = l + 64 * (m + 4 * q);
                const int sx = (((p >> 1) & 7) << 4) | (((p >> 4) & 1) << 3);
                *(float2*)(lds + p * 128 + (w8 ^ sx)) = v[m][q];
            }
        }
    }
    __syncthreads();

    // cooperative store: per iter, lanes {x group} x {j=0..7} cover one full
    // 128B line per column.  x = 8w + (l&7) + 128i, j = l>>3.
    {
        const int j = l >> 3;
        const int xbase = (w << 3) + (l & 7);
        const bool sw = (w >> 1) & 1;             // == (x>>4)&1, wave-uniform
        #pragma unroll
        for (int i = 0; i < 8; ++i) {
            const int x   = xbase + (i << 7);
            const int s70 = ((x >> 1) & 7) << 4;
            float4 g = *(const float4*)(lds + x * 128 + ((16 * j) ^ s70));
            if (sw) g = make_float4(g.z, g.w, g.x, g.y);
            *(float4*)(T + ib + (long long)x * 1024 + y0 + 2 * j) = g;
        }
    }
}

// ---------------- K2: column pass, registers end-to-end (verified R5/R6) -----
// 256 thr = 4 waves, one column per wave, 32KB LDS, zero block barriers.
__global__ __launch_bounds__(256, 4) void k2_cols_H(float2* __restrict__ T,
                                                    const float2* __restrict__ Htab,
                                                    const float* __restrict__ wl) {
    __shared__ float4 ldsb[2048];                 // 32KB
    char* lds = (char*)ldsb;
    const int t = threadIdx.x, w = t >> 6, l = t & 63;
    const int img = blockIdx.x >> 8;
    const int x   = ((blockIdx.x & 255) << 2) + w;
    const int lamIdx = img % 3;
    char* cb = lds + 8192 * w;
    float2* col = T + ((long long)img << 20) + (long long)x * 1024;

    // global -> regs in round-A layout (512B/instr coalesced)
    float2 v[4][4];
    #pragma unroll
    for (int k = 0; k < 4; ++k) {
        #pragma unroll
        for (int r = 0; r < 4; ++r)
            v[k][r] = col[l + 64 * (k + 4 * r)];
    }
    fftA<-1>(cb, l, v); WSYNC();
    fftB<-1>(cb, l);    WSYNC();

    // H loads issued here (cover latency under round C)
    float2 h[4][4];
    if (Htab) {
        const float2* hrow = Htab + ((long long)lamIdx << 20) + (long long)x * 1024;
        #pragma unroll
        for (int m = 0; m < 4; ++m) {
            #pragma unroll
            for (int q = 0; q < 4; ++q)
                h[m][q] = hrow[l + 64 * (m + 4 * q)];
        }
    } else {
        const float lam = wl[lamIdx];
        #pragma unroll
        for (int m = 0; m < 4; ++m) {
            #pragma unroll
            for (int q = 0; q < 4; ++q)
                h[m][q] = computeH(lam, l + 64 * (m + 4 * q), x);
        }
    }

    ldsToRegs(cb, l, v);
    fftC<-1>(l, v);

    // *H in registers
    #pragma unroll
    for (int m = 0; m < 4; ++m) {
        #pragma unroll
        for (int q = 0; q < 4; ++q) {
            float2 a = v[m][q], hh = h[m][q];
            v[m][q] = make_float2(a.x * hh.x - a.y * hh.y, a.x * hh.y + a.y * hh.x);
        }
    }
    WSYNC();   // order C-reads before inverse A-writes

    fftA<1>(cb, l, v); WSYNC();
    fftB<1>(cb, l);    WSYNC();
    ldsToRegs(cb, l, v);
    fftC<1>(l, v);

    // direct register store (coalesced 512B/instr)
    #pragma unroll
    for (int m = 0; m < 4; ++m) {
        #pragma unroll
        for (int q = 0; q < 4; ++q)
            col[l + 64 * (m + 4 * q)] = v[m][q];
    }
}

// ---------------- K3: full-line gather + row iFFT + direct plane store -------
__global__ __launch_bounds__(1024) void k3_irows_T16(const float2* __restrict__ T,
                                                     float* __restrict__ outr,
                                                     float* __restrict__ outi) {
    extern __shared__ char lds[];                 // 131072 bytes
    const int t = threadIdx.x, w = t >> 6, l = t & 63;
    const int img = blockIdx.x >> 6;
    const int y0  = (blockIdx.x & 63) << 4;
    const long long ib = (long long)img << 20;

    // gather: thread t = column t; read 16 complex (128B, line-aligned)
    {
        const float4* src = (const float4*)(T + ib + (long long)t * 1024 + y0);
        const int sx = SW(t);
        #pragma unroll
        for (int p = 0; p < 8; ++p) {
            float4 g = src[p];
            *(float2*)(lds + 8192 * (2 * p)     + sx) = make_float2(g.x, g.y);
            *(float2*)(lds + 8192 * (2 * p + 1) + sx) = make_float2(g.z, g.w);
        }
    }
    __syncthreads();

    char* cb = lds + 8192 * w;                    // wave w owns row y0+w
    float2 v[4][4];
    ldsToRegs(cb, l, v);
    fftA<1>(cb, l, v); WSYNC();
    fftB<1>(cb, l);    WSYNC();
    ldsToRegs(cb, l, v);
    fftC<1>(l, v);

    // direct store to planes (256B/instr coalesced dword stores)
    float* pr = outr + ib + (long long)(y0 + w) * 1024;
    float* pi = outi + ib + (long long)(y0 + w) * 1024;
    #pragma unroll
    for (int m = 0; m < 4; ++m) {
        #pragma unroll
        for (int q = 0; q < 4; ++q) {
            const int p = l + 64 * (m + 4 * q);
            pr[p] = v[m][q].x;
            pi[p] = v[m][q].y;
        }
    }
}

// ---------------- launch ------------------------------------------------------
extern "C" void kernel_launch(void* const* d_in, const int* in_sizes, int n_in,
                              void* d_out, int out_size, void* d_ws, size_t ws_size,
                              hipStream_t stream) {
    const float* xr = (const float*)d_in[0];
    const float* xi = (const float*)d_in[1];
    const float* wl = (const float*)d_in[2];
    float* out = (float*)d_out;

    const size_t planeElems = (size_t)NIMG * 1024 * 1024;          // 24M
    float2* wsC = (float2*)d_ws;                                   // 192 MB
    const size_t needC = planeElems * sizeof(float2);
    const size_t needH = (size_t)3 * 1024 * 1024 * sizeof(float2); // 24 MB
    float2* Htab = nullptr;
    if (ws_size >= needC + needH) {
        Htab = (float2*)((char*)d_ws + needC);
        build_H_T<<<12288, 256, 0, stream>>>(Htab, wl);
    }
    k1_rows_T16<<<NIMG * 64, 1024, 131072, stream>>>(xr, xi, wsC);
    k2_cols_H<<<NIMG * 256, 256, 0, stream>>>(wsC, Htab, wl);
    k3_irows_T16<<<NIMG * 64, 1024, 131072, stream>>>(wsC, out, out + planeElems);
}